// Round 1
// baseline (866.598 us; speedup 1.0000x reference)
//
#include <hip/hip_runtime.h>

// GCNConv: out[v] = sum_{(u->v)} x[u] * rsqrt(deg(u)*deg(v))
// N=100000 nodes, E=1600000 edges, D=128 features, fp32.

#define D_FEAT 128

__global__ void degree_kernel(const int* __restrict__ src,
                              float* __restrict__ deg, int E) {
    int i = blockIdx.x * blockDim.x + threadIdx.x;
    if (i < E) atomicAdd(&deg[src[i]], 1.0f);
}

__global__ void inv_sqrt_kernel(float* __restrict__ deg, int N) {
    int i = blockIdx.x * blockDim.x + threadIdx.x;
    if (i < N) deg[i] = rsqrtf(fmaxf(deg[i], 1.0f));
}

// One 128-thread block (2 waves) per edge; thread f handles feature f.
// x-read is fully coalesced (128 consecutive floats); atomics are to 128
// consecutive floats of out[dst].
__global__ void scatter_kernel(const float* __restrict__ x,
                               const int* __restrict__ src,
                               const int* __restrict__ dst,
                               const float* __restrict__ isd,
                               float* __restrict__ out, int E) {
    int e = blockIdx.x;
    if (e >= E) return;
    int f = threadIdx.x;
    int s = src[e];
    int d = dst[e];
    float coef = isd[s] * isd[d];
    float val = x[(long)s * D_FEAT + f] * coef;
    atomicAdd(&out[(long)d * D_FEAT + f], val);
}

extern "C" void kernel_launch(void* const* d_in, const int* in_sizes, int n_in,
                              void* d_out, int out_size, void* d_ws, size_t ws_size,
                              hipStream_t stream) {
    const float* x   = (const float*)d_in[0];
    const int*   src = (const int*)d_in[1];
    const int*   dst = (const int*)d_in[2];
    float* out = (float*)d_out;

    int N = in_sizes[0] / D_FEAT;   // 100000
    int E = in_sizes[1];            // 1600000

    float* deg = (float*)d_ws;      // reused in-place as isd after inv_sqrt

    // d_ws and d_out are poisoned 0xAA before every launch — zero them.
    hipMemsetAsync(deg, 0, (size_t)N * sizeof(float), stream);
    hipMemsetAsync(out, 0, (size_t)out_size * sizeof(float), stream);

    degree_kernel<<<(E + 255) / 256, 256, 0, stream>>>(src, deg, E);
    inv_sqrt_kernel<<<(N + 255) / 256, 256, 0, stream>>>(deg, N);
    scatter_kernel<<<E, D_FEAT, 0, stream>>>(x, src, dst, deg, out, E);
}

// Round 2
// 367.159 us; speedup vs baseline: 2.3603x; 2.3603x over previous
//
#include <hip/hip_runtime.h>

// GCNConv: out[v] = isd[v] * sum_{(u->v)} x[u] * isd[u],  isd = rsqrt(max(outdeg,1))
// N=100000 nodes, E=1600000 edges, D=128 fp32.
//
// Strategy: bucket edges by dst (counting, CAP=32 + overflow list), then a
// register-accumulating gather kernel writes each output row exactly once.
// No fp32 atomics on the 512B payload (round-1 bottleneck: WRITE_SIZE=800MB
// write-through atomic storm).

#define D_FEAT 128
#define CAP 32
#define NODES_PER_BLOCK 8   // 256 threads, 32 threads (float4 lanes) per node

__global__ void build_kernel(const int* __restrict__ src, const int* __restrict__ dst,
                             int* __restrict__ deg, int* __restrict__ cnt,
                             int* __restrict__ bucket, int2* __restrict__ ovf,
                             int* __restrict__ novf, int E) {
    int i = blockIdx.x * blockDim.x + threadIdx.x;
    if (i >= E) return;
    int s = src[i], d = dst[i];
    atomicAdd(&deg[s], 1);                 // out-degree histogram
    int slot = atomicAdd(&cnt[d], 1);      // in-bucket slot
    if (slot < CAP) {
        bucket[d * CAP + slot] = s;
    } else {
        int o = atomicAdd(novf, 1);        // rare Poisson(16) tail
        ovf[o] = make_int2(s, d);
    }
}

__global__ void isd_kernel(const int* __restrict__ deg, float* __restrict__ isd, int N) {
    int i = blockIdx.x * blockDim.x + threadIdx.x;
    if (i < N) isd[i] = rsqrtf(fmaxf((float)deg[i], 1.0f));
}

// 8 nodes per 256-thread block; 32 threads per node, float4 per thread.
__global__ void gather_kernel(const float4* __restrict__ x4,
                              const int* __restrict__ cnt,
                              const int* __restrict__ bucket,
                              const float* __restrict__ isd,
                              float4* __restrict__ out4, int N) {
    __shared__ int   sh_idx[NODES_PER_BLOCK * CAP];
    __shared__ float sh_w[NODES_PER_BLOCK * CAP];
    int t = threadIdx.x;
    int node_slot = t >> 5;            // 0..7
    int lane = t & 31;                 // float4 lane within the 128-float row
    int d = blockIdx.x * NODES_PER_BLOCK + node_slot;

    int c = 0;
    if (d < N) {
        c = min(cnt[d], CAP);
        if (lane < c) {                // cooperative stage: CAP==32 == group width
            int s = bucket[d * CAP + lane];
            sh_idx[node_slot * CAP + lane] = s;
            sh_w[node_slot * CAP + lane] = isd[s];
        }
    }
    __syncthreads();
    if (d >= N) return;

    float4 acc = {0.f, 0.f, 0.f, 0.f};
    #pragma unroll 4
    for (int k = 0; k < c; ++k) {
        int s   = sh_idx[node_slot * CAP + k];   // broadcast LDS read (free)
        float w = sh_w[node_slot * CAP + k];
        float4 v = x4[s * 32 + lane];            // 512B coalesced row gather
        acc.x += v.x * w; acc.y += v.y * w;
        acc.z += v.z * w; acc.w += v.w * w;
    }
    float wd = isd[d];
    acc.x *= wd; acc.y *= wd; acc.z *= wd; acc.w *= wd;
    out4[d * 32 + lane] = acc;                   // single non-atomic row write
}

// Tail edges of nodes with in-degree > CAP: atomic scatter (tiny count).
__global__ void overflow_kernel(const float* __restrict__ x,
                                const float* __restrict__ isd,
                                const int2* __restrict__ ovf,
                                const int* __restrict__ novf,
                                float* __restrict__ out) {
    int n = *novf;
    for (int e = blockIdx.x; e < n; e += gridDim.x) {
        int2 sd = ovf[e];
        float coef = isd[sd.x] * isd[sd.y];
        atomicAdd(&out[sd.y * D_FEAT + threadIdx.x],
                  x[sd.x * D_FEAT + threadIdx.x] * coef);
    }
}

// ---- Round-1 fallback (used only if ws_size is too small for buckets) ----
__global__ void fb_degree_kernel(const int* __restrict__ src,
                                 float* __restrict__ deg, int E) {
    int i = blockIdx.x * blockDim.x + threadIdx.x;
    if (i < E) atomicAdd(&deg[src[i]], 1.0f);
}
__global__ void fb_inv_sqrt_kernel(float* __restrict__ deg, int N) {
    int i = blockIdx.x * blockDim.x + threadIdx.x;
    if (i < N) deg[i] = rsqrtf(fmaxf(deg[i], 1.0f));
}
__global__ void fb_scatter_kernel(const float* __restrict__ x,
                                  const int* __restrict__ src,
                                  const int* __restrict__ dst,
                                  const float* __restrict__ isd,
                                  float* __restrict__ out, int E) {
    int e = blockIdx.x;
    if (e >= E) return;
    int f = threadIdx.x;
    int s = src[e], d = dst[e];
    float coef = isd[s] * isd[d];
    atomicAdd(&out[(long)d * D_FEAT + f], x[(long)s * D_FEAT + f] * coef);
}

extern "C" void kernel_launch(void* const* d_in, const int* in_sizes, int n_in,
                              void* d_out, int out_size, void* d_ws, size_t ws_size,
                              hipStream_t stream) {
    const float* x   = (const float*)d_in[0];
    const int*   src = (const int*)d_in[1];
    const int*   dst = (const int*)d_in[2];
    float* out = (float*)d_out;

    int N = in_sizes[0] / D_FEAT;   // 100000
    int E = in_sizes[1];            // 1600000

    // ws layout (bytes)
    size_t off_deg    = 0;
    size_t off_cnt    = off_deg + (size_t)N * 4;
    size_t off_isd    = off_cnt + (size_t)N * 4;
    size_t off_novf   = off_isd + (size_t)N * 4;
    size_t off_bucket = off_novf + 16;
    size_t off_ovf    = off_bucket + (size_t)N * CAP * 4;
    size_t needed     = off_ovf + (size_t)E * 8;

    if (ws_size < needed) {
        // Fallback: round-1 atomic scatter (needs only N floats of ws).
        float* deg = (float*)d_ws;
        hipMemsetAsync(deg, 0, (size_t)N * sizeof(float), stream);
        hipMemsetAsync(out, 0, (size_t)out_size * sizeof(float), stream);
        fb_degree_kernel<<<(E + 255) / 256, 256, 0, stream>>>(src, deg, E);
        fb_inv_sqrt_kernel<<<(N + 255) / 256, 256, 0, stream>>>(deg, N);
        fb_scatter_kernel<<<E, D_FEAT, 0, stream>>>(x, src, dst, deg, out, E);
        return;
    }

    char* ws = (char*)d_ws;
    int*   deg    = (int*)(ws + off_deg);
    int*   cnt    = (int*)(ws + off_cnt);
    float* isd    = (float*)(ws + off_isd);
    int*   novf   = (int*)(ws + off_novf);
    int*   bucket = (int*)(ws + off_bucket);
    int2*  ovf    = (int2*)(ws + off_ovf);

    // Zero only the counters (bucket slots are written before read; out is
    // fully written by gather_kernel).
    hipMemsetAsync(ws, 0, off_novf + 16, stream);

    build_kernel<<<(E + 255) / 256, 256, 0, stream>>>(src, dst, deg, cnt,
                                                      bucket, ovf, novf, E);
    isd_kernel<<<(N + 255) / 256, 256, 0, stream>>>(deg, isd, N);
    gather_kernel<<<(N + NODES_PER_BLOCK - 1) / NODES_PER_BLOCK, 256, 0, stream>>>(
        (const float4*)x, cnt, bucket, isd, (float4*)out, N);
    overflow_kernel<<<64, D_FEAT, 0, stream>>>(x, isd, ovf, novf, out);
}

// Round 3
// 337.999 us; speedup vs baseline: 2.5639x; 1.0863x over previous
//
#include <hip/hip_runtime.h>

// GCNConv: out[v] = isd[v] * sum_{(u->v)} x[u] * isd[u],  isd = rsqrt(max(outdeg,1))
// N=100000, E=1600000, D=128 fp32.
//
// R1 -> R2: bucketed gather killed the 800MB atomic write storm (866 -> 367us).
// R2 -> R3: build_kernel's scattered bucket stores showed 147MB WRITE_SIZE
// (11x amplification: 12.8MB bucket array thrashing 4MB per-XCD L2). Fix:
// dst-range slicing with slice = blockIdx % 8 (XCD round-robin heuristic) so
// each XCD's L2 holds only a 1.6MB bucket slice; edge-index re-reads (8x) are
// LLC-absorbed.

#define D_FEAT 128
#define CAP 32
#define NODES_PER_BLOCK 8   // gather: 256 threads, 32 lanes (float4) per node
#define NSLICES 8
#define BPS 512             // build blocks per slice

__global__ void build_kernel(const int* __restrict__ src, const int* __restrict__ dst,
                             int* __restrict__ deg, int* __restrict__ cnt,
                             int* __restrict__ bucket, int2* __restrict__ ovf,
                             int* __restrict__ novf, int E, int sliceSz) {
    int slice = blockIdx.x & (NSLICES - 1);     // XCD round-robin heuristic
    int chunk = blockIdx.x >> 3;                // 0..BPS-1
    int lo = slice * sliceSz;
    int hi = lo + sliceSz;
    int chunkSz = (E + BPS - 1) / BPS;
    int beg = chunk * chunkSz;
    int end = min(E, beg + chunkSz);

    for (int i = beg + (int)threadIdx.x; i < end; i += blockDim.x) {
        int s = src[i];
        int d = dst[i];
        if (d >= lo && d < hi) {                // this slice owns dst-range
            int slot = atomicAdd(&cnt[d], 1);
            if (slot < CAP) {
                bucket[d * CAP + slot] = s;
            } else {
                int o = atomicAdd(novf, 1);     // rare Poisson(16) tail
                ovf[o] = make_int2(s, d);
            }
        }
        if (s >= lo && s < hi) {                // out-degree histogram, same locality
            atomicAdd(&deg[s], 1);
        }
    }
}

__global__ void isd_kernel(const int* __restrict__ deg, float* __restrict__ isd, int N) {
    int i = blockIdx.x * blockDim.x + threadIdx.x;
    if (i < N) isd[i] = rsqrtf(fmaxf((float)deg[i], 1.0f));
}

// 8 nodes per 256-thread block; 32 threads per node, float4 per thread.
__global__ void gather_kernel(const float4* __restrict__ x4,
                              const int* __restrict__ cnt,
                              const int* __restrict__ bucket,
                              const float* __restrict__ isd,
                              float4* __restrict__ out4, int N) {
    __shared__ int   sh_idx[NODES_PER_BLOCK * CAP];
    __shared__ float sh_w[NODES_PER_BLOCK * CAP];
    int t = threadIdx.x;
    int node_slot = t >> 5;
    int lane = t & 31;
    int d = blockIdx.x * NODES_PER_BLOCK + node_slot;

    int c = 0;
    if (d < N) {
        c = min(cnt[d], CAP);
        if (lane < c) {
            int s = bucket[d * CAP + lane];
            sh_idx[node_slot * CAP + lane] = s;
            sh_w[node_slot * CAP + lane] = isd[s];
        }
    }
    __syncthreads();
    if (d >= N) return;

    float4 acc = {0.f, 0.f, 0.f, 0.f};
    #pragma unroll 4
    for (int k = 0; k < c; ++k) {
        int s   = sh_idx[node_slot * CAP + k];   // broadcast LDS read
        float w = sh_w[node_slot * CAP + k];
        float4 v = x4[s * 32 + lane];            // 512B coalesced row gather
        acc.x += v.x * w; acc.y += v.y * w;
        acc.z += v.z * w; acc.w += v.w * w;
    }
    float wd = isd[d];
    acc.x *= wd; acc.y *= wd; acc.z *= wd; acc.w *= wd;
    out4[d * 32 + lane] = acc;                   // single non-atomic row write
}

__global__ void overflow_kernel(const float* __restrict__ x,
                                const float* __restrict__ isd,
                                const int2* __restrict__ ovf,
                                const int* __restrict__ novf,
                                float* __restrict__ out) {
    int n = *novf;
    for (int e = blockIdx.x; e < n; e += gridDim.x) {
        int2 sd = ovf[e];
        float coef = isd[sd.x] * isd[sd.y];
        atomicAdd(&out[sd.y * D_FEAT + threadIdx.x],
                  x[sd.x * D_FEAT + threadIdx.x] * coef);
    }
}

// ---- fallback (ws too small): round-1 atomic scatter ----
__global__ void fb_degree_kernel(const int* __restrict__ src,
                                 float* __restrict__ deg, int E) {
    int i = blockIdx.x * blockDim.x + threadIdx.x;
    if (i < E) atomicAdd(&deg[src[i]], 1.0f);
}
__global__ void fb_inv_sqrt_kernel(float* __restrict__ deg, int N) {
    int i = blockIdx.x * blockDim.x + threadIdx.x;
    if (i < N) deg[i] = rsqrtf(fmaxf(deg[i], 1.0f));
}
__global__ void fb_scatter_kernel(const float* __restrict__ x,
                                  const int* __restrict__ src,
                                  const int* __restrict__ dst,
                                  const float* __restrict__ isd,
                                  float* __restrict__ out, int E) {
    int e = blockIdx.x;
    if (e >= E) return;
    int f = threadIdx.x;
    int s = src[e], d = dst[e];
    float coef = isd[s] * isd[d];
    atomicAdd(&out[(long)d * D_FEAT + f], x[(long)s * D_FEAT + f] * coef);
}

extern "C" void kernel_launch(void* const* d_in, const int* in_sizes, int n_in,
                              void* d_out, int out_size, void* d_ws, size_t ws_size,
                              hipStream_t stream) {
    const float* x   = (const float*)d_in[0];
    const int*   src = (const int*)d_in[1];
    const int*   dst = (const int*)d_in[2];
    float* out = (float*)d_out;

    int N = in_sizes[0] / D_FEAT;   // 100000
    int E = in_sizes[1];            // 1600000

    size_t off_deg    = 0;
    size_t off_cnt    = off_deg + (size_t)N * 4;
    size_t off_isd    = off_cnt + (size_t)N * 4;
    size_t off_novf   = off_isd + (size_t)N * 4;
    size_t off_bucket = off_novf + 16;
    size_t off_ovf    = off_bucket + (size_t)N * CAP * 4;
    size_t needed     = off_ovf + (size_t)E * 8;

    if (ws_size < needed) {
        float* deg = (float*)d_ws;
        hipMemsetAsync(deg, 0, (size_t)N * sizeof(float), stream);
        hipMemsetAsync(out, 0, (size_t)out_size * sizeof(float), stream);
        fb_degree_kernel<<<(E + 255) / 256, 256, 0, stream>>>(src, deg, E);
        fb_inv_sqrt_kernel<<<(N + 255) / 256, 256, 0, stream>>>(deg, N);
        fb_scatter_kernel<<<E, D_FEAT, 0, stream>>>(x, src, dst, deg, out, E);
        return;
    }

    char* ws = (char*)d_ws;
    int*   deg    = (int*)(ws + off_deg);
    int*   cnt    = (int*)(ws + off_cnt);
    float* isd    = (float*)(ws + off_isd);
    int*   novf   = (int*)(ws + off_novf);
    int*   bucket = (int*)(ws + off_bucket);
    int2*  ovf    = (int2*)(ws + off_ovf);

    hipMemsetAsync(ws, 0, off_novf + 16, stream);  // deg, cnt, (isd), novf

    int sliceSz = (N + NSLICES - 1) / NSLICES;
    build_kernel<<<NSLICES * BPS, 256, 0, stream>>>(src, dst, deg, cnt,
                                                    bucket, ovf, novf, E, sliceSz);
    isd_kernel<<<(N + 255) / 256, 256, 0, stream>>>(deg, isd, N);
    gather_kernel<<<(N + NODES_PER_BLOCK - 1) / NODES_PER_BLOCK, 256, 0, stream>>>(
        (const float4*)x, cnt, bucket, isd, (float4*)out, N);
    overflow_kernel<<<64, D_FEAT, 0, stream>>>(x, isd, ovf, novf, out);
}